// Round 3
// baseline (99.536 us; speedup 1.0000x reference)
//
#include <hip/hip_runtime.h>
#include <hip/hip_bf16.h>

// E3nnSimpleEdgeBlock, two-stage MFMA formulation.
// Stage 1 (MFMA, per v): G_{p,c}[e,w] = sum_u a_c[e,u] * Wp[u,v,w]   (A static!)
// Stage 2 (fp32 VALU, per v): acc[e,w] += b_c[e,v] * G_{p,c}[e,w] combos:
//   out0  += b0*G000 + b1x*G110x + b1y*G110y + b1z*G110z
//   out1x += b1x*G011 + b0*G101x + b1z*G111y - b1y*G111z
//   out1y += b1y*G011 + b0*G101y + b1x*G111z - b1z*G111x
//   out1z += b1z*G011 + b0*G101z + b1y*G111x - b1x*G111y
// Channel scales (C0, C1, 1/sqrt3, 1/sqrt6) pre-baked into the weight stream.
//
// mfma_f32_16x16x32_bf16 lane mapping (m89-verified):
//   A[row=l&15][k=8*(l>>4)+j]  B[k=8*(l>>4)+j][col=l&15]  D[row=4*(l>>4)+r][col=l&15]

typedef __attribute__((ext_vector_type(8))) short short8;   // 8 bf16 (4 VGPRs)
typedef __attribute__((ext_vector_type(4))) float f32x4;

static constexpr float C_OUT0    = 0.022097086912079608f; // 1/sqrt(2048)
static constexpr float C_OUT1    = 0.03125f;              // 1/sqrt(1024)
static constexpr float INV_SQRT3 = 0.57735026918962576f;
static constexpr float INV_SQRT6 = 0.40824829046386302f;

static __device__ __forceinline__ short bfbits(float x) {
    __hip_bfloat16 h = __float2bfloat16(x);
    return __builtin_bit_cast(short, h);
}

// ---------------------------------------------------------------------------
// prep: coalesced-read, scatter-write bf16 B-fragment stream in d_ws.
// Stream layout (unchanged from R2): for v, frag f (0..9), lane l: 8 bf16.
//   f = 2g + nf;  g: 0=W000 1=W110 2=W011 3=W101 4=W111;  w = nf*16 + (l&15)
//   element j: scale_g * Wg[(8*(l>>4)+j)*1024 + v*32 + w]
// ---------------------------------------------------------------------------
__global__ __launch_bounds__(256) void prep_weights(
    const float* __restrict__ W000, const float* __restrict__ W110,
    const float* __restrict__ W011, const float* __restrict__ W101,
    const float* __restrict__ W111, short* __restrict__ wsB)
{
    const int t = blockIdx.x * 256 + threadIdx.x;   // 0 .. 5*32768-1
    if (t >= 5 * 32768) return;
    const int g   = t >> 15;
    const int idx = t & 32767;          // u*1024 + v*32 + w
    const int u = idx >> 10, v = (idx >> 5) & 31, w = idx & 31;
    const float* Wp = (g == 0) ? W000 : (g == 1) ? W110 : (g == 2) ? W011
                    : (g == 3) ? W101 : W111;
    const float s = (g == 0) ? C_OUT0
                  : (g == 1) ? C_OUT0 * INV_SQRT3
                  : (g == 4) ? C_OUT1 * INV_SQRT6
                  :            C_OUT1 * INV_SQRT3;
    const int f = 2 * g + (w >> 4);
    const int l = ((u >> 3) << 4) | (w & 15);
    const int j = u & 7;
    wsB[(((v * 10 + f) * 64) + l) * 8 + j] = bfbits(s * Wp[idx]);
}

// ---------------------------------------------------------------------------
// main: 256 threads = 4 waves, 16 edges/wave, 64 edges/block.
// LDS reused: phase 1 stages x1 [64][33 float4]; then bT[v][comp][e] (32 KB).
// ---------------------------------------------------------------------------
__global__ __launch_bounds__(256) void e3nn_mfma2(
    const float* __restrict__ x1, const float* __restrict__ x2,
    const short8* __restrict__ wsB, float* __restrict__ out, int E)
{
    __shared__ float smemf[64 * 132];   // 33.8 KB, covers both phases
    float4* smem4 = (float4*)smemf;

    const int tid   = threadIdx.x;
    const int l     = tid & 63;
    const int wv    = tid >> 6;
    const int eBase = blockIdx.x * 64;

    // ---- phase 1: stage x1 tile, coalesced float4, padded stride 33 ----
    const float4* x1v = (const float4*)x1;
    for (int i = tid; i < 64 * 32; i += 256) {
        const int e = i >> 5, c4 = i & 31;
        float4 val = {0.f, 0.f, 0.f, 0.f};
        if (eBase + e < E) val = x1v[(size_t)(eBase + e) * 32 + c4];
        smem4[e * 33 + c4] = val;
    }
    __syncthreads();

    // ---- build static bf16 A-fragments (once per wave!) ----
    const int eloc = l & 15;
    const int u0   = (l >> 4) * 8;
    const float* row = smemf + (wv * 16 + eloc) * 132;
    short8 Aa0, Aa1x, Aa1y, Aa1z;
    #pragma unroll
    for (int j = 0; j < 8; ++j) {
        Aa0[j]  = bfbits(row[u0 + j]);
        Aa1x[j] = bfbits(row[32 + 3 * (u0 + j) + 0]);
        Aa1y[j] = bfbits(row[32 + 3 * (u0 + j) + 1]);
        Aa1z[j] = bfbits(row[32 + 3 * (u0 + j) + 2]);
    }
    __syncthreads();

    // ---- phase 2: bT[v][comp][e], comp = {b0, b1x, b1y, b1z} ----
    for (int i = tid; i < 64 * 128; i += 256) {
        const int e = i >> 7, r = i & 127;
        float val = 0.f;
        if (eBase + e < E) val = x2[(size_t)(eBase + e) * 128 + r];
        if (r < 32) {
            smemf[r * 256 + e] = val;                       // bT[v=r][0][e]
        } else {
            const int q = r - 32, vv = q / 3, c = q - 3 * vv;
            smemf[vv * 256 + (c + 1) * 64 + e] = val;       // bT[vv][c+1][e]
        }
    }
    __syncthreads();

    // ---- main K loop over v: 22 MFMAs + 32 f32x4 FMAs per v ----
    const f32x4 zero = {0.f, 0.f, 0.f, 0.f};
    f32x4 acc0[2]    = {zero, zero};
    f32x4 acc1[3][2] = {{zero, zero}, {zero, zero}, {zero, zero}};

    const short8* wb = wsB + l;
    const int be0 = wv * 16 + (l >> 4) * 4;   // lane's first D-row (local e)

    for (int v = 0; v < 32; ++v) {
        // b-vectors for this lane's 4 D-rows (broadcast reads, conflict-free)
        const float* bv = smemf + v * 256 + be0;
        const f32x4 b0v = *(const f32x4*)(bv);
        const f32x4 b1x = *(const f32x4*)(bv + 64);
        const f32x4 b1y = *(const f32x4*)(bv + 128);
        const f32x4 b1z = *(const f32x4*)(bv + 192);

        const short8* p = wb + v * 640;   // (v*10 + f)*64 + l
        #pragma unroll
        for (int nf = 0; nf < 2; ++nf) {
            const short8 B000 = p[(0 + nf) * 64];
            const short8 B110 = p[(2 + nf) * 64];
            const short8 B011 = p[(4 + nf) * 64];
            const short8 B101 = p[(6 + nf) * 64];
            const short8 B111 = p[(8 + nf) * 64];

            const f32x4 G000  = __builtin_amdgcn_mfma_f32_16x16x32_bf16(Aa0,  B000, zero, 0, 0, 0);
            const f32x4 G110x = __builtin_amdgcn_mfma_f32_16x16x32_bf16(Aa1x, B110, zero, 0, 0, 0);
            const f32x4 G110y = __builtin_amdgcn_mfma_f32_16x16x32_bf16(Aa1y, B110, zero, 0, 0, 0);
            const f32x4 G110z = __builtin_amdgcn_mfma_f32_16x16x32_bf16(Aa1z, B110, zero, 0, 0, 0);
            const f32x4 G011  = __builtin_amdgcn_mfma_f32_16x16x32_bf16(Aa0,  B011, zero, 0, 0, 0);
            const f32x4 G101x = __builtin_amdgcn_mfma_f32_16x16x32_bf16(Aa1x, B101, zero, 0, 0, 0);
            const f32x4 G101y = __builtin_amdgcn_mfma_f32_16x16x32_bf16(Aa1y, B101, zero, 0, 0, 0);
            const f32x4 G101z = __builtin_amdgcn_mfma_f32_16x16x32_bf16(Aa1z, B101, zero, 0, 0, 0);
            const f32x4 G111x = __builtin_amdgcn_mfma_f32_16x16x32_bf16(Aa1x, B111, zero, 0, 0, 0);
            const f32x4 G111y = __builtin_amdgcn_mfma_f32_16x16x32_bf16(Aa1y, B111, zero, 0, 0, 0);
            const f32x4 G111z = __builtin_amdgcn_mfma_f32_16x16x32_bf16(Aa1z, B111, zero, 0, 0, 0);

            acc0[nf]    += b0v * G000  + b1x * G110x + b1y * G110y + b1z * G110z;
            acc1[0][nf] += b1x * G011  + b0v * G101x + b1z * G111y - b1y * G111z;
            acc1[1][nf] += b1y * G011  + b0v * G101y + b1x * G111z - b1z * G111x;
            acc1[2][nf] += b1z * G011  + b0v * G101z + b1y * G111x - b1x * G111y;
        }
    }

    // ---- epilogue (scales pre-baked) ----
    #pragma unroll
    for (int nf = 0; nf < 2; ++nf) {
        const int w = nf * 16 + (l & 15);
        #pragma unroll
        for (int r = 0; r < 4; ++r) {
            const int ge = eBase + be0 + r;
            if (ge < E) {
                const size_t base = (size_t)ge * 128;
                out[base + w] = acc0[nf][r];
                out[base + 32 + 3 * w + 0] = acc1[0][nf][r];
                out[base + 32 + 3 * w + 1] = acc1[1][nf][r];
                out[base + 32 + 3 * w + 2] = acc1[2][nf][r];
            }
        }
    }
}

extern "C" void kernel_launch(void* const* d_in, const int* in_sizes, int n_in,
                              void* d_out, int out_size, void* d_ws, size_t ws_size,
                              hipStream_t stream) {
    const float* x1   = (const float*)d_in[0];
    const float* x2   = (const float*)d_in[1];
    const float* W000 = (const float*)d_in[2];
    const float* W110 = (const float*)d_in[3];
    const float* W011 = (const float*)d_in[4];
    const float* W101 = (const float*)d_in[5];
    const float* W111 = (const float*)d_in[6];
    float* out = (float*)d_out;

    const int E = in_sizes[0] / 128;

    hipLaunchKernelGGL(prep_weights, dim3((5 * 32768 + 255) / 256), dim3(256), 0, stream,
                       W000, W110, W011, W101, W111, (short*)d_ws);

    const int grid = (E + 63) / 64;
    hipLaunchKernelGGL(e3nn_mfma2, dim3(grid), dim3(256), 0, stream,
                       x1, x2, (const short8*)d_ws, out, E);
}

// Round 5
// 83.995 us; speedup vs baseline: 1.1850x; 1.1850x over previous
//
#include <hip/hip_runtime.h>
#include <hip/hip_bf16.h>

// E3nnSimpleEdgeBlock via bf16 MFMA (R2-proven datapath) + v-split occupancy fix.
//   out0[e,w]   = C0*( sum_uv W000[u,v,w] a0[u]b0[v] + IS3 * sum_uv W110[u,v,w] dot(a1[u],b1[v]) )
//   out1[e,w,k] = C1*( IS3*( sum W011 a0[u]b1[v,k] + sum W101 a1[u,k]b0[v] ) + IS6*sum W111 cross_k )
// GEMM view: M=16 edges/wave-tile, N=32 (2 frags), K=(v,ch,u). Per v, 11 bf16
// A-fragments built in-register; B-fragments precomputed (scales baked) in d_ws.
// v-split: waves (tile t, vhalf vh) — vh=0 does v=0..15, vh=1 does v=16..31;
// partial accumulators reduced through LDS. 2x the waves of R2 (6.1/SIMD).
//
// mfma_f32_16x16x32_bf16 lane mapping (m89-verified):
//   A[row=l&15][k=8*(l>>4)+j]  B[k=8*(l>>4)+j][col=l&15]  D[row=4*(l>>4)+r][col=l&15]

typedef __attribute__((ext_vector_type(8))) short short8;   // 8 bf16 (4 VGPRs)
typedef __attribute__((ext_vector_type(4))) float f32x4;

static constexpr float C_OUT0    = 0.022097086912079608f; // 1/sqrt(2048)
static constexpr float C_OUT1    = 0.03125f;              // 1/sqrt(1024)
static constexpr float INV_SQRT3 = 0.57735026918962576f;
static constexpr float INV_SQRT6 = 0.40824829046386302f;

static __device__ __forceinline__ short bfbits(float x) {
    __hip_bfloat16 h = __float2bfloat16(x);
    return __builtin_bit_cast(short, h);
}

// ---------------------------------------------------------------------------
// prep (identical to R3, post-timing-proven): coalesced-read, scatter-write
// bf16 B-fragment stream. Layout: for v, frag f (0..9), lane l: 8 bf16.
//   f = 2g + nf;  g: 0=W000 1=W110 2=W011 3=W101 4=W111;  w = nf*16 + (l&15)
//   element j: scale_g * Wg[(8*(l>>4)+j)*1024 + v*32 + w].  Total 327680 B.
// ---------------------------------------------------------------------------
__global__ __launch_bounds__(256) void prep_weights(
    const float* __restrict__ W000, const float* __restrict__ W110,
    const float* __restrict__ W011, const float* __restrict__ W101,
    const float* __restrict__ W111, short* __restrict__ wsB)
{
    const int t = blockIdx.x * 256 + threadIdx.x;   // 0 .. 5*32768-1
    if (t >= 5 * 32768) return;
    const int g   = t >> 15;
    const int idx = t & 32767;          // u*1024 + v*32 + w
    const int u = idx >> 10, v = (idx >> 5) & 31, w = idx & 31;
    const float* Wp = (g == 0) ? W000 : (g == 1) ? W110 : (g == 2) ? W011
                    : (g == 3) ? W101 : W111;
    const float s = (g == 0) ? C_OUT0
                  : (g == 1) ? C_OUT0 * INV_SQRT3
                  : (g == 4) ? C_OUT1 * INV_SQRT6
                  :            C_OUT1 * INV_SQRT3;
    const int f = 2 * g + (w >> 4);
    const int l = ((u >> 3) << 4) | (w & 15);
    const int j = u & 7;
    wsB[(((v * 10 + f) * 64) + l) * 8 + j] = bfbits(s * Wp[idx]);
}

// ---------------------------------------------------------------------------
// main: 256 threads = 4 waves = 2 edge-tiles (16 edges) x 2 v-halves.
// LDS buffer (16.9 KB) reused: x1 stage -> bs[e][v] float4 -> reduction scratch.
// ---------------------------------------------------------------------------
__global__ __launch_bounds__(256) void e3nn_vsplit(
    const float* __restrict__ x1, const float* __restrict__ x2,
    const short8* __restrict__ wsB, float* __restrict__ out, int E)
{
    __shared__ float smemf[32 * 132];   // 16.9 KB
    float4* smem4 = (float4*)smemf;

    const int tid   = threadIdx.x;
    const int l     = tid & 63;
    const int wv    = tid >> 6;
    const int t     = wv & 1;    // edge-tile within block
    const int vh    = wv >> 1;   // v-half: 0 -> v 0..15, 1 -> v 16..31
    const int eBase = blockIdx.x * 32;

    // ---- phase 1: stage x1 tile (32 edges x 32 float4), padded stride 33 ----
    const float4* x1v = (const float4*)x1;
    for (int i = tid; i < 32 * 32; i += 256) {
        const int e = i >> 5, c4 = i & 31;
        float4 val = {0.f, 0.f, 0.f, 0.f};
        if (eBase + e < E) val = x1v[(size_t)(eBase + e) * 32 + c4];
        smem4[e * 33 + c4] = val;
    }
    __syncthreads();

    // ---- hoist per-lane a-values (f32) into registers ----
    const int eloc = l & 15;
    const int u0   = (l >> 4) * 8;
    const float* row = smemf + (t * 16 + eloc) * 132;
    float a0r[8], a1r[3][8];
    #pragma unroll
    for (int j = 0; j < 8; ++j) {
        a0r[j] = row[u0 + j];
        #pragma unroll
        for (int c = 0; c < 3; ++c)
            a1r[c][j] = row[32 + 3 * (u0 + j) + c];
    }
    __syncthreads();

    // ---- phase 2: bs[e][v] = {b0, b1x, b1y, b1z} (overwrites x1 stage) ----
    for (int i = tid; i < 32 * 128; i += 256) {
        const int e = i >> 7, r = i & 127;
        float val = 0.f;
        if (eBase + e < E) val = x2[(size_t)(eBase + e) * 128 + r];
        if (r < 32) {
            smemf[e * 132 + r * 4] = val;
        } else {
            const int q = r - 32, vv = q / 3, c = q - 3 * vv;
            smemf[e * 132 + vv * 4 + 1 + c] = val;
        }
    }
    __syncthreads();

    // ---- v-loop over this wave's half: 16 iters, 22 accumulating MFMAs ----
    const f32x4 zero = {0.f, 0.f, 0.f, 0.f};
    f32x4 acc0[2]    = {zero, zero};
    f32x4 acc1[3][2] = {{zero, zero}, {zero, zero}, {zero, zero}};

    const short8* wb    = wsB + l;
    const float4* bsrow = smem4 + (t * 16 + eloc) * 33;

    for (int v = vh * 16; v < vh * 16 + 16; ++v) {
        const float4 b = bsrow[v];
        const short8* p = wb + v * 640;   // (v*10 + f)*64 + l
        short8 Bf[10];
        #pragma unroll
        for (int i = 0; i < 10; ++i) Bf[i] = p[i * 64];

        const float bv[3] = {b.y, b.z, b.w};
        short8 A;

        // out0 ch0: a0[u]*b0[v]
        #pragma unroll
        for (int j = 0; j < 8; ++j) A[j] = bfbits(a0r[j] * b.x);
        acc0[0] = __builtin_amdgcn_mfma_f32_16x16x32_bf16(A, Bf[0], acc0[0], 0, 0, 0);
        acc0[1] = __builtin_amdgcn_mfma_f32_16x16x32_bf16(A, Bf[1], acc0[1], 0, 0, 0);

        // out0 ch1: dot(a1[u], b1[v])
        #pragma unroll
        for (int j = 0; j < 8; ++j)
            A[j] = bfbits(a1r[0][j] * b.y + a1r[1][j] * b.z + a1r[2][j] * b.w);
        acc0[0] = __builtin_amdgcn_mfma_f32_16x16x32_bf16(A, Bf[2], acc0[0], 0, 0, 0);
        acc0[1] = __builtin_amdgcn_mfma_f32_16x16x32_bf16(A, Bf[3], acc0[1], 0, 0, 0);

        // out1 component kx
        #pragma unroll
        for (int kx = 0; kx < 3; ++kx) {
            const int ii = (kx + 1) % 3, jj = (kx + 2) % 3;
            short8 A011, A101, A111;
            #pragma unroll
            for (int j = 0; j < 8; ++j) {
                A011[j] = bfbits(a0r[j] * bv[kx]);
                A101[j] = bfbits(a1r[kx][j] * b.x);
                A111[j] = bfbits(a1r[ii][j] * bv[jj] - a1r[jj][j] * bv[ii]);
            }
            acc1[kx][0] = __builtin_amdgcn_mfma_f32_16x16x32_bf16(A011, Bf[4], acc1[kx][0], 0, 0, 0);
            acc1[kx][1] = __builtin_amdgcn_mfma_f32_16x16x32_bf16(A011, Bf[5], acc1[kx][1], 0, 0, 0);
            acc1[kx][0] = __builtin_amdgcn_mfma_f32_16x16x32_bf16(A101, Bf[6], acc1[kx][0], 0, 0, 0);
            acc1[kx][1] = __builtin_amdgcn_mfma_f32_16x16x32_bf16(A101, Bf[7], acc1[kx][1], 0, 0, 0);
            acc1[kx][0] = __builtin_amdgcn_mfma_f32_16x16x32_bf16(A111, Bf[8], acc1[kx][0], 0, 0, 0);
            acc1[kx][1] = __builtin_amdgcn_mfma_f32_16x16x32_bf16(A111, Bf[9], acc1[kx][1], 0, 0, 0);
        }
    }

    // ---- reduce the two v-halves through LDS (stride-33 rows: conflict-free) ----
    __syncthreads();   // all waves done reading bs[] before scratch reuse

    float* red = smemf;
    const int rbase = (t * 64 + l) * 33;   // max 127*33+31 = 4222 < 4224
    if (vh == 1) {
        #pragma unroll
        for (int nf = 0; nf < 2; ++nf)
            #pragma unroll
            for (int r = 0; r < 4; ++r) {
                red[rbase + (0 + nf) * 4 + r] = acc0[nf][r];
                red[rbase + (2 + nf) * 4 + r] = acc1[0][nf][r];
                red[rbase + (4 + nf) * 4 + r] = acc1[1][nf][r];
                red[rbase + (6 + nf) * 4 + r] = acc1[2][nf][r];
            }
    }
    __syncthreads();

    // ---- epilogue from vh=0 waves only (scales pre-baked into weights) ----
    if (vh == 0) {
        const int be0 = t * 16 + (l >> 4) * 4;
        #pragma unroll
        for (int nf = 0; nf < 2; ++nf) {
            const int w = nf * 16 + (l & 15);
            #pragma unroll
            for (int r = 0; r < 4; ++r) {
                const int ge = eBase + be0 + r;
                if (ge < E) {
                    const size_t base = (size_t)ge * 128;
                    out[base + w] =
                        acc0[nf][r] + red[rbase + (0 + nf) * 4 + r];
                    out[base + 32 + 3 * w + 0] =
                        acc1[0][nf][r] + red[rbase + (2 + nf) * 4 + r];
                    out[base + 32 + 3 * w + 1] =
                        acc1[1][nf][r] + red[rbase + (4 + nf) * 4 + r];
                    out[base + 32 + 3 * w + 2] =
                        acc1[2][nf][r] + red[rbase + (6 + nf) * 4 + r];
                }
            }
        }
    }
}

extern "C" void kernel_launch(void* const* d_in, const int* in_sizes, int n_in,
                              void* d_out, int out_size, void* d_ws, size_t ws_size,
                              hipStream_t stream) {
    const float* x1   = (const float*)d_in[0];
    const float* x2   = (const float*)d_in[1];
    const float* W000 = (const float*)d_in[2];
    const float* W110 = (const float*)d_in[3];
    const float* W011 = (const float*)d_in[4];
    const float* W101 = (const float*)d_in[5];
    const float* W111 = (const float*)d_in[6];
    float* out = (float*)d_out;

    const int E = in_sizes[0] / 128;

    hipLaunchKernelGGL(prep_weights, dim3((5 * 32768 + 255) / 256), dim3(256), 0, stream,
                       W000, W110, W011, W101, W111, (short*)d_ws);

    const int grid = (E + 31) / 32;
    hipLaunchKernelGGL(e3nn_vsplit, dim3(grid), dim3(256), 0, stream,
                       x1, x2, (const short8*)d_ws, out, E);
}